// Round 15
// baseline (3982.856 us; speedup 1.0000x reference)
//
#include <hip/hip_runtime.h>
#include <hip/hip_bf16.h>
#include <stdint.h>

#define NTOK 8192   // B*T
#define DM   1024   // model dim
#define NE   8      // experts
#define DI   2048   // expert inner dim
#define NL   2      // layers
#define NV   32000  // vocab

typedef __attribute__((ext_vector_type(8))) __bf16 bf16x8;
typedef __attribute__((ext_vector_type(4))) float  f32x4;
typedef __attribute__((ext_vector_type(4))) uint32_t u32x4;
typedef unsigned short u16;

__device__ __forceinline__ u16 f2bf(float f) {
  uint32_t u = __builtin_bit_cast(uint32_t, f);
  return (u16)((u + 0x7fffu + ((u >> 16) & 1u)) >> 16);  // RNE
}

// full-line stream stores (sc0 sc1 nt): 16B/lane, consecutive lanes cover
// contiguous memory -> whole 128B lines written -> no write-allocate RFO
__device__ __forceinline__ void nts_f32x4(float* p, f32x4 v) {
  asm volatile("global_store_dwordx4 %0, %1, off sc0 sc1 nt"
               :: "v"(p), "v"(v) : "memory");
}
__device__ __forceinline__ void nts_b128(u16* p, u32x4 v) {
  asm volatile("global_store_dwordx4 %0, %1, off sc0 sc1 nt"
               :: "v"(p), "v"(v) : "memory");
}

__device__ __forceinline__ void gload_lds16(const u16* g, void* l) {
  __builtin_amdgcn_global_load_lds(
      (const __attribute__((address_space(1))) void*)g,
      (__attribute__((address_space(3))) void*)l, 16, 0, 0);
}

// bijective chunked XCD swizzle (m204)
__device__ __forceinline__ int xcd_swz(int orig, int nwg) {
  const int x = orig & 7, i = orig >> 3;
  const int q = nwg >> 3, r = nwg & 7;
  return (x < r ? x * (q + 1) : r * (q + 1) + (x - r) * q) + i;
}

// ---------------------------------------------------------------------------
// R15: 128(M) x 256(N) tile, 256 threads = 4 waves, wave-tile 128x64 (same
// per-wave geometry/acc as R12). LDS: 3 unit-buffers x 24 KB = 72 KB ->
// 2 BLOCKS/CU: the co-resident block's waves fill the ~1750 cyc/K-half
// barrier stall measured on the 1-block/CU R12 structure (R6 tested this
// under the RFO-flooded store path where it couldn't show; store path is
// now clean). Pipeline: stage g+2 while computing g, counted vmcnt(6)
// steady, vmcnt(0) only at the last unit. [rows][32] + slot swizzle
// (BANK_CONFLICT=0 measured).
// EPILOGUE: LDS-staged (R12 win), 2 passes x 64 rows (64 KB <= 72 KB):
// scatter acc -> barrier -> linear readback -> full-line nt stores with
// fused bias/gelu.
// EPI: 0 = +bias -> f32 (head), 1 = gelu -> bf16 (gemm1), 2 = f32 strided.
// ---------------------------------------------------------------------------
template <int EPI>
__global__ __launch_bounds__(256, 2) void k_gemm(
    const u16* __restrict__ A0, const u16* __restrict__ W0,
    void* __restrict__ O0, const float* __restrict__ bias,
    int K, int mBlks, int nBlks,
    size_t aStride, size_t wStride, size_t oStride, int ldOut) {
  extern __shared__ char lds[];   // 3 x 24576 B
  const int logical = xcd_swz(blockIdx.x, gridDim.x);
  const int perE = mBlks * nBlks;
  const int e    = logical / perE;
  const int rem  = logical - e * perE;
  const int mb   = rem / nBlks;        // m outer
  const int nb   = rem - mb * nBlks;   // n inner
  const int rowBase = mb * 128;
  const int colBase = nb * 256;
  const u16* A = A0 + (size_t)e * aStride;
  const u16* W = W0 + (size_t)e * wStride;

  const int t = threadIdx.x, lane = t & 63, wn = t >> 6;   // wave = n-strip
  const int fr = lane & 15, kg = lane >> 4;

  // ---- staging: chunk c -> row=c>>2, slotL=c&3; linear LDS dest c*16;
  // global slot = slotL ^ ((row>>2)&3) (inverse swizzle at source)
  const u16* gA[2]; int loA[2];
#pragma unroll
  for (int i = 0; i < 2; ++i) {
    const int c = t + 256 * i, row = c >> 2;
    const int gs = (c & 3) ^ ((row >> 2) & 3);
    gA[i] = A + (size_t)(rowBase + row) * K + gs * 8;
    loA[i] = c * 16;
  }
  const u16* gB[4]; int loB[4];
#pragma unroll
  for (int j = 0; j < 4; ++j) {
    const int c = t + 256 * j, row = c >> 2;
    const int gs = (c & 3) ^ ((row >> 2) & 3);
    gB[j] = W + (size_t)(colBase + row) * K + gs * 8;
    loB[j] = 8192 + c * 16;
  }

  auto stage = [&](int g, int buf) {
    char* dst = lds + buf * 24576;
#pragma unroll
    for (int i = 0; i < 2; ++i) gload_lds16(gA[i] + (size_t)g * 32, dst + loA[i]);
#pragma unroll
    for (int j = 0; j < 4; ++j) gload_lds16(gB[j] + (size_t)g * 32, dst + loB[j]);
  };

  // ---- fragment read offsets: addr = row*64 + (kg^((fr>>2)&3))*16
  const int swzo = (kg ^ ((fr >> 2) & 3)) * 16;
  const int aOff = fr * 64 + swzo;                     // + mi*1024 (16 rows)
  const int bOff = 8192 + (wn * 64 + fr) * 64 + swzo;  // + ni*1024

  f32x4 acc[8][4] = {};
  const int NG = K >> 5;

  auto compute = [&](int buf) {
    const char* base = lds + buf * 24576;
    bf16x8 af[8], bv[4];
#pragma unroll
    for (int mi = 0; mi < 8; ++mi) af[mi] = *(const bf16x8*)(base + aOff + mi * 1024);
#pragma unroll
    for (int ni = 0; ni < 4; ++ni) bv[ni] = *(const bf16x8*)(base + bOff + ni * 1024);
    __builtin_amdgcn_s_setprio(1);
#pragma unroll
    for (int mi = 0; mi < 8; ++mi)
#pragma unroll
      for (int ni = 0; ni < 4; ++ni)
        acc[mi][ni] = __builtin_amdgcn_mfma_f32_16x16x32_bf16(
            af[mi], bv[ni], acc[mi][ni], 0, 0, 0);
    __builtin_amdgcn_s_setprio(0);
  };

  // prologue: 2 units in flight (12 loads/thread outstanding)
  stage(0, 0);
  stage(1, 1);

  int buf = 0;
#pragma unroll 1
  for (int g = 0; g < NG - 1; ++g) {
    asm volatile("s_waitcnt vmcnt(6)" ::: "memory");  // own unit-g loads done
    __builtin_amdgcn_s_barrier();
    asm volatile("" ::: "memory");
    if (g + 2 < NG) {
      int b2 = buf + 2; if (b2 >= 3) b2 -= 3;
      stage(g + 2, b2);          // overwrites buf of g-1: safe after barrier
    }
    compute(buf);
    ++buf; if (buf >= 3) buf = 0;
  }
  asm volatile("s_waitcnt vmcnt(0)" ::: "memory");
  __builtin_amdgcn_s_barrier();
  asm volatile("" ::: "memory");
  compute(buf);

  // ---- LDS-staged epilogue: 2 passes x 64 rows (64 KB) --------------------
  float* ep = (float*)lds;
  const int colL0 = wn * 64 + fr;
  __syncthreads();   // mainloop LDS reads drained on all waves
#pragma unroll 1
  for (int p = 0; p < 2; ++p) {
#pragma unroll
    for (int mm = 0; mm < 4; ++mm) {
      const int mi = 4 * p + mm;
#pragma unroll
      for (int ni = 0; ni < 4; ++ni) {
        const int rl = mm * 16 + (kg << 2);
        const int cl = colL0 + ni * 16;
#pragma unroll
        for (int j = 0; j < 4; ++j)
          ep[(rl + j) * 256 + cl] = acc[mi][ni][j];
      }
    }
    __syncthreads();
    if (EPI == 1) {
      u16* O = (u16*)O0 + (size_t)e * oStride;
#pragma unroll
      for (int ii = 0; ii < 8; ++ii) {
        const int chunk = t + 256 * ii;        // 32B chunks: 64*32 = 2048
        const int rl = chunk >> 5;
        const int cl = (chunk & 31) << 3;      // 8 floats
        const f32x4 v0 = *(const f32x4*)(ep + rl * 256 + cl);
        const f32x4 v1 = *(const f32x4*)(ep + rl * 256 + cl + 4);
        float gv[8];
#pragma unroll
        for (int j = 0; j < 4; ++j) {
          gv[j]     = 0.5f * v0[j] * (1.0f + erff(v0[j] * 0.70710678118654752f));
          gv[4 + j] = 0.5f * v1[j] * (1.0f + erff(v1[j] * 0.70710678118654752f));
        }
        u32x4 pk;
        pk.x = (uint32_t)f2bf(gv[0]) | ((uint32_t)f2bf(gv[1]) << 16);
        pk.y = (uint32_t)f2bf(gv[2]) | ((uint32_t)f2bf(gv[3]) << 16);
        pk.z = (uint32_t)f2bf(gv[4]) | ((uint32_t)f2bf(gv[5]) << 16);
        pk.w = (uint32_t)f2bf(gv[6]) | ((uint32_t)f2bf(gv[7]) << 16);
        const int row = rowBase + p * 64 + rl;
        nts_b128(&O[(size_t)row * ldOut + colBase + cl], pk);
      }
    } else {
      float* O = (float*)O0 + (EPI == 2 ? (size_t)e * oStride : (size_t)0);
#pragma unroll
      for (int ii = 0; ii < 16; ++ii) {
        const int chunk = t + 256 * ii;        // 16B chunks: 64*64 = 4096
        const int rl = chunk >> 6;
        const int cl = (chunk & 63) << 2;      // 4 floats
        f32x4 v = *(const f32x4*)(ep + rl * 256 + cl);
        if (EPI == 0) v += *(const f32x4*)(bias + colBase + cl);
        const int row = rowBase + p * 64 + rl;
        nts_f32x4(&O[(size_t)row * ldOut + colBase + cl], v);
      }
    }
    __syncthreads();   // readback done before next pass overwrites LDS
  }
}

// transpose+convert: in f32 [z][R][C] -> out bf16 [z][C][R]  (R12 version)
__global__ void k_transcvt(const float* __restrict__ in, u16* __restrict__ out,
                           int R, int C) {
  const size_t bo = (size_t)blockIdx.z * R * C;
  in += bo; out += bo;
  __shared__ u16 tile[32][33];
  const int tx = threadIdx.x, ty = threadIdx.y;
  const int r0 = blockIdx.y << 5, c0 = blockIdx.x << 5;
#pragma unroll
  for (int j = 0; j < 4; ++j) {
    const int r = r0 + ty + j * 8;
    tile[ty + j * 8][tx] = f2bf(in[(size_t)r * C + c0 + tx]);
  }
  __syncthreads();
#pragma unroll
  for (int j = 0; j < 4; ++j) {
    const int c = c0 + ty + j * 8;
    out[(size_t)c * R + r0 + tx] = tile[tx][ty + j * 8];
  }
}

// embedding gather
__global__ void k_gather(const int* __restrict__ x, const float* __restrict__ emb,
                         float* __restrict__ h) {
  const int n = blockIdx.x, t = threadIdx.x;
  const int id = x[n];
  ((float4*)(h + (size_t)n * DM))[t] = ((const float4*)(emb + (size_t)id * DM))[t];
}

// fused LayerNorm (f32) -> xn bf16, + gating logits + softmax -> rw
__global__ void k_lngate(const float* __restrict__ h, const float* __restrict__ g,
                         const float* __restrict__ b, const float* __restrict__ gw,
                         const float* __restrict__ gb, u16* __restrict__ xnb,
                         float* __restrict__ rw) {
  const int n = blockIdx.x, t = threadIdx.x;
  const int wave = t >> 6, lane = t & 63;
  const float4 v = ((const float4*)(h + (size_t)n * DM))[t];
  float s = v.x + v.y + v.z + v.w;
  float q = v.x * v.x + v.y * v.y + v.z * v.z + v.w * v.w;
#pragma unroll
  for (int o = 32; o; o >>= 1) { s += __shfl_down(s, o, 64); q += __shfl_down(q, o, 64); }
  __shared__ float red[8];
  if (lane == 0) { red[wave] = s; red[wave + 4] = q; }
  __syncthreads();
  s = red[0] + red[1] + red[2] + red[3];
  q = red[4] + red[5] + red[6] + red[7];
  const float mu = s * (1.0f / DM);
  const float var = q * (1.0f / DM) - mu * mu;
  const float rs = rsqrtf(var + 1e-5f);
  const float4 gg = ((const float4*)g)[t];
  const float4 bb = ((const float4*)b)[t];
  float xv[4];
  xv[0] = (v.x - mu) * rs * gg.x + bb.x;
  xv[1] = (v.y - mu) * rs * gg.y + bb.y;
  xv[2] = (v.z - mu) * rs * gg.z + bb.z;
  xv[3] = (v.w - mu) * rs * gg.w + bb.w;
  ushort4 o4;
  o4.x = f2bf(xv[0]); o4.y = f2bf(xv[1]); o4.z = f2bf(xv[2]); o4.w = f2bf(xv[3]);
  ((ushort4*)(xnb + (size_t)n * DM))[t] = o4;
  float p[8];
#pragma unroll
  for (int e = 0; e < 8; ++e) p[e] = 0.0f;
  const float* gwp = gw + (size_t)t * 32;
#pragma unroll
  for (int j = 0; j < 4; ++j)
#pragma unroll
    for (int e = 0; e < 8; ++e) p[e] += xv[j] * gwp[j * 8 + e];
#pragma unroll
  for (int e = 0; e < 8; ++e)
#pragma unroll
    for (int o = 32; o; o >>= 1) p[e] += __shfl_down(p[e], o, 64);
  __shared__ float pr[4][8];
  if (lane == 0) {
#pragma unroll
    for (int e = 0; e < 8; ++e) pr[wave][e] = p[e];
  }
  __syncthreads();
  if (t == 0) {
    float lg[8], m = -1e30f;
#pragma unroll
    for (int e = 0; e < 8; ++e) {
      lg[e] = pr[0][e] + pr[1][e] + pr[2][e] + pr[3][e] + gb[e];
      m = fmaxf(m, lg[e]);
    }
    float ss = 0.0f;
#pragma unroll
    for (int e = 0; e < 8; ++e) { lg[e] = expf(lg[e] - m); ss += lg[e]; }
    const float inv = 1.0f / ss;
#pragma unroll
    for (int e = 0; e < 8; ++e) rw[(size_t)n * NE + e] = lg[e] * inv;
  }
}

// h += sum_e rw[n][e] * eo[n][e][:]; also emit h in bf16 for the head GEMM
__global__ void k_agg(float* __restrict__ h, u16* __restrict__ hbf,
                      const float* __restrict__ eo, const float* __restrict__ rw) {
  const int n = blockIdx.x, t = threadIdx.x;
  float w[8];
#pragma unroll
  for (int e = 0; e < 8; ++e) w[e] = rw[(size_t)n * NE + e];
  const f32x4* eo4 = (const f32x4*)(eo + (size_t)n * NE * DM);
  f32x4 a = ((f32x4*)(h + (size_t)n * DM))[t];
#pragma unroll
  for (int e = 0; e < 8; ++e) {
    const f32x4 xv = __builtin_nontemporal_load(&eo4[e * (DM / 4) + t]);
    a += w[e] * xv;
  }
  ((f32x4*)(h + (size_t)n * DM))[t] = a;
  ushort4 o4;
  o4.x = f2bf(a.x); o4.y = f2bf(a.y); o4.z = f2bf(a.z); o4.w = f2bf(a.w);
  ((ushort4*)(hbf + (size_t)n * DM))[t] = o4;
}

extern "C" void kernel_launch(void* const* d_in, const int* in_sizes, int n_in,
                              void* d_out, int out_size, void* d_ws, size_t ws_size,
                              hipStream_t stream) {
  const int*   x      = (const int*)d_in[0];
  const float* emb    = (const float*)d_in[1];
  const float* ln_g   = (const float*)d_in[2];
  const float* ln_b   = (const float*)d_in[3];
  const float* gate_w = (const float*)d_in[4];
  const float* gate_b = (const float*)d_in[5];
  const float* w1     = (const float*)d_in[6];
  const float* w2     = (const float*)d_in[7];
  const float* head_w = (const float*)d_in[8];
  const float* head_b = (const float*)d_in[9];

  float* logits  = (float*)d_out;
  float* experts = logits + (size_t)NTOK * NV;

  char* p = (char*)d_ws;
  auto carve = [&](size_t bytes) -> void* {
    void* r = (void*)p; p += (bytes + 255) & ~(size_t)255; return r;
  };
  float* h   = (float*)carve((size_t)NTOK * DM * 4);
  u16*   hbf = (u16*)  carve((size_t)NTOK * DM * 2);
  u16*   xnb = (u16*)  carve((size_t)NTOK * DM * 2);
  float* rw  = (float*)carve((size_t)NTOK * NE * 4);
  u16*   w1t = (u16*)  carve((size_t)NE * DM * DI * 2);
  u16*   w2t = (u16*)  carve((size_t)NE * DM * DI * 2);
  u16*   hwt = (u16*)  carve((size_t)NV * DM * 2);
  const size_t fixed = (size_t)(p - (char*)d_ws);
  const size_t eactOne = (size_t)NTOK * DI * 2;
  const bool batched = ws_size >= fixed + eactOne * NE;
  u16* eact = (u16*)carve(batched ? eactOne * NE : eactOne);

  const int LDSB = 73728;  // 3 x 24 KB
  (void)hipFuncSetAttribute((const void*)k_gemm<0>,
                            hipFuncAttributeMaxDynamicSharedMemorySize, LDSB);
  (void)hipFuncSetAttribute((const void*)k_gemm<1>,
                            hipFuncAttributeMaxDynamicSharedMemorySize, LDSB);
  (void)hipFuncSetAttribute((const void*)k_gemm<2>,
                            hipFuncAttributeMaxDynamicSharedMemorySize, LDSB);

  const int MB = NTOK / 128;  // 64 m-blocks

  k_gather<<<dim3(NTOK), dim3(256), 0, stream>>>(x, emb, h);

  for (int l = 0; l < NL; ++l) {
    k_lngate<<<dim3(NTOK), dim3(256), 0, stream>>>(
        h, ln_g + (size_t)l * DM, ln_b + (size_t)l * DM,
        gate_w + (size_t)l * DM * NE, gate_b + (size_t)l * NE, xnb, rw);
    k_transcvt<<<dim3(DI / 32, DM / 32, NE), dim3(32, 8), 0, stream>>>(
        w1 + (size_t)l * NE * DM * DI, w1t, DM, DI);
    k_transcvt<<<dim3(DM / 32, DI / 32, NE), dim3(32, 8), 0, stream>>>(
        w2 + (size_t)l * NE * DM * DI, w2t, DI, DM);
    float* expertsL = experts + (size_t)l * NTOK * NE * DM;
    if (batched) {
      k_gemm<1><<<dim3(NE * MB * (DI / 256)), dim3(256), LDSB, stream>>>(
          xnb, w1t, eact, nullptr, DM, MB, DI / 256,
          (size_t)0, (size_t)DM * DI, (size_t)NTOK * DI, DI);
      k_gemm<2><<<dim3(NE * MB * (DM / 256)), dim3(256), LDSB, stream>>>(
          eact, w2t, expertsL, nullptr, DI, MB, DM / 256,
          (size_t)NTOK * DI, (size_t)DM * DI, (size_t)DM, NE * DM);
    } else {
      for (int e = 0; e < NE; ++e) {
        k_gemm<1><<<dim3(MB * (DI / 256)), dim3(256), LDSB, stream>>>(
            xnb, w1t + (size_t)e * DM * DI, eact, nullptr, DM, MB, DI / 256,
            (size_t)0, (size_t)0, (size_t)0, DI);
        k_gemm<2><<<dim3(MB * (DM / 256)), dim3(256), LDSB, stream>>>(
            eact, w2t + (size_t)e * DM * DI, expertsL + (size_t)e * DM, nullptr,
            DI, MB, DM / 256, (size_t)0, (size_t)0, (size_t)0, NE * DM);
      }
    }
    k_agg<<<dim3(NTOK), dim3(256), 0, stream>>>(h, hbf, expertsL, rw);
  }

  k_transcvt<<<dim3(NV / 32, DM / 32, 1), dim3(32, 8), 0, stream>>>(head_w, hwt, DM, NV);
  k_gemm<0><<<dim3(MB * (NV / 256)), dim3(256), LDSB, stream>>>(
      hbf, hwt, logits, head_b, DM, MB, NV / 256,
      (size_t)0, (size_t)0, (size_t)0, NV);
}

// Round 16
// 2186.060 us; speedup vs baseline: 1.8219x; 1.8219x over previous
//
#include <hip/hip_runtime.h>
#include <hip/hip_bf16.h>
#include <stdint.h>

#define NTOK 8192   // B*T
#define DM   1024   // model dim
#define NE   8      // experts
#define DI   2048   // expert inner dim
#define NL   2      // layers
#define NV   32000  // vocab

typedef __attribute__((ext_vector_type(8))) __bf16 bf16x8;
typedef __attribute__((ext_vector_type(4))) float  f32x4;
typedef __attribute__((ext_vector_type(4))) uint32_t u32x4;
typedef unsigned short u16;

__device__ __forceinline__ u16 f2bf(float f) {
  uint32_t u = __builtin_bit_cast(uint32_t, f);
  return (u16)((u + 0x7fffu + ((u >> 16) & 1u)) >> 16);  // RNE
}

// full-line stream stores, `nt` ONLY (R16 fix): R15 counters showed sc0
// (write-through) caused exactly 4x HBM write amplification (each 16B store
// = one 64B sector transaction, no L2 combining; head WRITE 4.19GB vs
// 1.05GB output). nt alone = normal write-back combining + evict-first
// allocation (no operand-panel eviction); full-line pattern avoids RFO.
__device__ __forceinline__ void nts_f32x4(float* p, f32x4 v) {
  asm volatile("global_store_dwordx4 %0, %1, off nt"
               :: "v"(p), "v"(v) : "memory");
}
__device__ __forceinline__ void nts_b128(u16* p, u32x4 v) {
  asm volatile("global_store_dwordx4 %0, %1, off nt"
               :: "v"(p), "v"(v) : "memory");
}

__device__ __forceinline__ void gload_lds16(const u16* g, void* l) {
  __builtin_amdgcn_global_load_lds(
      (const __attribute__((address_space(1))) void*)g,
      (__attribute__((address_space(3))) void*)l, 16, 0, 0);
}

// bijective chunked XCD swizzle (m204)
__device__ __forceinline__ int xcd_swz(int orig, int nwg) {
  const int x = orig & 7, i = orig >> 3;
  const int q = nwg >> 3, r = nwg & 7;
  return (x < r ? x * (q + 1) : r * (q + 1) + (x - r) * q) + i;
}

// ---------------------------------------------------------------------------
// 256x256 tile GEMM, 512 threads = 8 waves (2M x 4N), wave-tile 128x64.
// Mainloop (R12, best measured): K-half=32 units, 4 buffers (g&3), stage g+3
// while computing g, counted vmcnt(8) steady / 4 / 0 peel. One barrier per
// K-half (finer cadences regressed twice). [rows][32] layout + slot swizzle.
// EPILOGUE: LDS-staged (R12 -11% win): scatter acc to LDS [128][256] f32 per
// wm-half, barrier, linear readback, coalesced full-line nt stores with
// fused bias/gelu. R16: store flags sc0 sc1 nt -> nt (kills 4x write ampl).
// EPI: 0 = +bias -> f32 (head), 1 = gelu -> bf16 (gemm1), 2 = f32 strided.
// ---------------------------------------------------------------------------
template <int EPI>
__global__ __launch_bounds__(512, 1) void k_gemm256(
    const u16* __restrict__ A0, const u16* __restrict__ W0,
    void* __restrict__ O0, const float* __restrict__ bias,
    int K, int mBlks, int nBlks,
    size_t aStride, size_t wStride, size_t oStride, int ldOut) {
  extern __shared__ char lds[];   // 4 x 32768 B (mainloop) / 128KB (epilogue)
  const int logical = xcd_swz(blockIdx.x, gridDim.x);
  const int perE = mBlks * nBlks;
  const int e    = logical / perE;
  const int rem  = logical - e * perE;
  const int mb   = rem / nBlks;        // m outer
  const int nb   = rem - mb * nBlks;   // n inner
  const int rowBase = mb * 256;
  const int colBase = nb * 256;
  const u16* A = A0 + (size_t)e * aStride;
  const u16* W = W0 + (size_t)e * wStride;

  const int t = threadIdx.x, lane = t & 63, wave = t >> 6;
  const int wm = wave >> 2, wn = wave & 3;   // wave tile (wm*128, wn*64)
  const int fr = lane & 15, kg = lane >> 4;

  // ---- staging: chunk c (0..1023 per operand) -> row=c>>2, slotL=c&3;
  // linear LDS dest c*16; global slot = slotL ^ ((row>>2)&3) (inverse swz)
  const u16* gA[2]; const u16* gB[2]; int loA[2], loB[2];
#pragma unroll
  for (int i = 0; i < 2; ++i) {
    const int c = t + 512 * i, row = c >> 2;
    const int gs = (c & 3) ^ ((row >> 2) & 3);
    gA[i] = A + (size_t)(rowBase + row) * K + gs * 8;
    gB[i] = W + (size_t)(colBase + row) * K + gs * 8;
    loA[i] = c * 16;
    loB[i] = 16384 + c * 16;
  }

  auto stage = [&](int g) {
    char* dst = lds + (g & 3) * 32768;
#pragma unroll
    for (int i = 0; i < 2; ++i) {
      gload_lds16(gA[i] + (size_t)g * 32, dst + loA[i]);
      gload_lds16(gB[i] + (size_t)g * 32, dst + loB[i]);
    }
  };

  // ---- fragment read offsets: addr = row*64 + (kg^((fr>>2)&3))*16
  const int swzo = (kg ^ ((fr >> 2) & 3)) * 16;
  const int aOff = (wm * 128 + fr) * 64 + swzo;           // + mi*1024 (16 rows)
  const int bOff = 16384 + (wn * 64 + fr) * 64 + swzo;    // + ni*1024

  f32x4 acc[8][4] = {};
  const int NG = K >> 5;   // K-halves (>= 32 for all our shapes)

  auto khalf = [&](int g, bool doStage) {
    __builtin_amdgcn_s_barrier();
    asm volatile("" ::: "memory");
    const char* base = lds + (g & 3) * 32768;
    bf16x8 af[8], bv[4];
#pragma unroll
    for (int mi = 0; mi < 8; ++mi) af[mi] = *(const bf16x8*)(base + aOff + mi * 1024);
#pragma unroll
    for (int ni = 0; ni < 4; ++ni) bv[ni] = *(const bf16x8*)(base + bOff + ni * 1024);
    if (doStage) stage(g + 3);
    __builtin_amdgcn_s_setprio(1);
#pragma unroll
    for (int mi = 0; mi < 8; ++mi)
#pragma unroll
      for (int ni = 0; ni < 4; ++ni)
        acc[mi][ni] = __builtin_amdgcn_mfma_f32_16x16x32_bf16(
            af[mi], bv[ni], acc[mi][ni], 0, 0, 0);
    __builtin_amdgcn_s_setprio(0);
  };

  // prologue: 3 units in flight (12 loads/thread outstanding)
  stage(0); stage(1); stage(2);

#pragma unroll 1
  for (int g = 0; g < NG - 3; ++g) {
    asm volatile("s_waitcnt vmcnt(8)" ::: "memory");  // unit g resident
    khalf(g, true);
  }
  asm volatile("s_waitcnt vmcnt(8)" ::: "memory");
  khalf(NG - 3, false);
  asm volatile("s_waitcnt vmcnt(4)" ::: "memory");
  khalf(NG - 2, false);
  asm volatile("s_waitcnt vmcnt(0)" ::: "memory");
  khalf(NG - 1, false);

  // ---- LDS-staged epilogue ------------------------------------------------
  float* ep = (float*)lds;
  const int colL0 = wn * 64 + fr;
  __syncthreads();   // mainloop LDS reads drained on all waves
#pragma unroll 1
  for (int p = 0; p < 2; ++p) {
    if (wm == p) {
#pragma unroll
      for (int mi = 0; mi < 8; ++mi)
#pragma unroll
        for (int ni = 0; ni < 4; ++ni) {
          const int rl = mi * 16 + (kg << 2);
          const int cl = colL0 + ni * 16;
#pragma unroll
          for (int j = 0; j < 4; ++j)
            ep[(rl + j) * 256 + cl] = acc[mi][ni][j];
        }
    }
    __syncthreads();
    if (EPI == 1) {
      u16* O = (u16*)O0 + (size_t)e * oStride;
#pragma unroll
      for (int ii = 0; ii < 8; ++ii) {
        const int chunk = t + 512 * ii;        // 32B chunks: 128*32 = 4096
        const int rl = chunk >> 5;
        const int cl = (chunk & 31) << 3;      // 8 floats
        const f32x4 v0 = *(const f32x4*)(ep + rl * 256 + cl);
        const f32x4 v1 = *(const f32x4*)(ep + rl * 256 + cl + 4);
        float gv[8];
#pragma unroll
        for (int j = 0; j < 4; ++j) {
          gv[j]     = 0.5f * v0[j] * (1.0f + erff(v0[j] * 0.70710678118654752f));
          gv[4 + j] = 0.5f * v1[j] * (1.0f + erff(v1[j] * 0.70710678118654752f));
        }
        u32x4 pk;
        pk.x = (uint32_t)f2bf(gv[0]) | ((uint32_t)f2bf(gv[1]) << 16);
        pk.y = (uint32_t)f2bf(gv[2]) | ((uint32_t)f2bf(gv[3]) << 16);
        pk.z = (uint32_t)f2bf(gv[4]) | ((uint32_t)f2bf(gv[5]) << 16);
        pk.w = (uint32_t)f2bf(gv[6]) | ((uint32_t)f2bf(gv[7]) << 16);
        const int row = rowBase + p * 128 + rl;
        nts_b128(&O[(size_t)row * ldOut + colBase + cl], pk);
      }
    } else {
      float* O = (float*)O0 + (EPI == 2 ? (size_t)e * oStride : (size_t)0);
#pragma unroll
      for (int ii = 0; ii < 16; ++ii) {
        const int chunk = t + 512 * ii;        // 16B chunks: 128*64 = 8192
        const int rl = chunk >> 6;
        const int cl = (chunk & 63) << 2;      // 4 floats
        f32x4 v = *(const f32x4*)(ep + rl * 256 + cl);
        if (EPI == 0) v += *(const f32x4*)(bias + colBase + cl);
        const int row = rowBase + p * 128 + rl;
        nts_f32x4(&O[(size_t)row * ldOut + colBase + cl], v);
      }
    }
    __syncthreads();   // readback done before next pass overwrites LDS
  }
}

// transpose+convert: in f32 [z][R][C] -> out bf16 [z][C][R]  (R12 version)
__global__ void k_transcvt(const float* __restrict__ in, u16* __restrict__ out,
                           int R, int C) {
  const size_t bo = (size_t)blockIdx.z * R * C;
  in += bo; out += bo;
  __shared__ u16 tile[32][33];
  const int tx = threadIdx.x, ty = threadIdx.y;
  const int r0 = blockIdx.y << 5, c0 = blockIdx.x << 5;
#pragma unroll
  for (int j = 0; j < 4; ++j) {
    const int r = r0 + ty + j * 8;
    tile[ty + j * 8][tx] = f2bf(in[(size_t)r * C + c0 + tx]);
  }
  __syncthreads();
#pragma unroll
  for (int j = 0; j < 4; ++j) {
    const int c = c0 + ty + j * 8;
    out[(size_t)c * R + r0 + tx] = tile[tx][ty + j * 8];
  }
}

// embedding gather
__global__ void k_gather(const int* __restrict__ x, const float* __restrict__ emb,
                         float* __restrict__ h) {
  const int n = blockIdx.x, t = threadIdx.x;
  const int id = x[n];
  ((float4*)(h + (size_t)n * DM))[t] = ((const float4*)(emb + (size_t)id * DM))[t];
}

// fused LayerNorm (f32) -> xn bf16, + gating logits + softmax -> rw
__global__ void k_lngate(const float* __restrict__ h, const float* __restrict__ g,
                         const float* __restrict__ b, const float* __restrict__ gw,
                         const float* __restrict__ gb, u16* __restrict__ xnb,
                         float* __restrict__ rw) {
  const int n = blockIdx.x, t = threadIdx.x;
  const int wave = t >> 6, lane = t & 63;
  const float4 v = ((const float4*)(h + (size_t)n * DM))[t];
  float s = v.x + v.y + v.z + v.w;
  float q = v.x * v.x + v.y * v.y + v.z * v.z + v.w * v.w;
#pragma unroll
  for (int o = 32; o; o >>= 1) { s += __shfl_down(s, o, 64); q += __shfl_down(q, o, 64); }
  __shared__ float red[8];
  if (lane == 0) { red[wave] = s; red[wave + 4] = q; }
  __syncthreads();
  s = red[0] + red[1] + red[2] + red[3];
  q = red[4] + red[5] + red[6] + red[7];
  const float mu = s * (1.0f / DM);
  const float var = q * (1.0f / DM) - mu * mu;
  const float rs = rsqrtf(var + 1e-5f);
  const float4 gg = ((const float4*)g)[t];
  const float4 bb = ((const float4*)b)[t];
  float xv[4];
  xv[0] = (v.x - mu) * rs * gg.x + bb.x;
  xv[1] = (v.y - mu) * rs * gg.y + bb.y;
  xv[2] = (v.z - mu) * rs * gg.z + bb.z;
  xv[3] = (v.w - mu) * rs * gg.w + bb.w;
  ushort4 o4;
  o4.x = f2bf(xv[0]); o4.y = f2bf(xv[1]); o4.z = f2bf(xv[2]); o4.w = f2bf(xv[3]);
  ((ushort4*)(xnb + (size_t)n * DM))[t] = o4;
  float p[8];
#pragma unroll
  for (int e = 0; e < 8; ++e) p[e] = 0.0f;
  const float* gwp = gw + (size_t)t * 32;
#pragma unroll
  for (int j = 0; j < 4; ++j)
#pragma unroll
    for (int e = 0; e < 8; ++e) p[e] += xv[j] * gwp[j * 8 + e];
#pragma unroll
  for (int e = 0; e < 8; ++e)
#pragma unroll
    for (int o = 32; o; o >>= 1) p[e] += __shfl_down(p[e], o, 64);
  __shared__ float pr[4][8];
  if (lane == 0) {
#pragma unroll
    for (int e = 0; e < 8; ++e) pr[wave][e] = p[e];
  }
  __syncthreads();
  if (t == 0) {
    float lg[8], m = -1e30f;
#pragma unroll
    for (int e = 0; e < 8; ++e) {
      lg[e] = pr[0][e] + pr[1][e] + pr[2][e] + pr[3][e] + gb[e];
      m = fmaxf(m, lg[e]);
    }
    float ss = 0.0f;
#pragma unroll
    for (int e = 0; e < 8; ++e) { lg[e] = expf(lg[e] - m); ss += lg[e]; }
    const float inv = 1.0f / ss;
#pragma unroll
    for (int e = 0; e < 8; ++e) rw[(size_t)n * NE + e] = lg[e] * inv;
  }
}

// h += sum_e rw[n][e] * eo[n][e][:]; also emit h in bf16 for the head GEMM
__global__ void k_agg(float* __restrict__ h, u16* __restrict__ hbf,
                      const float* __restrict__ eo, const float* __restrict__ rw) {
  const int n = blockIdx.x, t = threadIdx.x;
  float w[8];
#pragma unroll
  for (int e = 0; e < 8; ++e) w[e] = rw[(size_t)n * NE + e];
  const f32x4* eo4 = (const f32x4*)(eo + (size_t)n * NE * DM);
  f32x4 a = ((f32x4*)(h + (size_t)n * DM))[t];
#pragma unroll
  for (int e = 0; e < 8; ++e) {
    const f32x4 xv = __builtin_nontemporal_load(&eo4[e * (DM / 4) + t]);
    a += w[e] * xv;
  }
  ((f32x4*)(h + (size_t)n * DM))[t] = a;
  ushort4 o4;
  o4.x = f2bf(a.x); o4.y = f2bf(a.y); o4.z = f2bf(a.z); o4.w = f2bf(a.w);
  ((ushort4*)(hbf + (size_t)n * DM))[t] = o4;
}

extern "C" void kernel_launch(void* const* d_in, const int* in_sizes, int n_in,
                              void* d_out, int out_size, void* d_ws, size_t ws_size,
                              hipStream_t stream) {
  const int*   x      = (const int*)d_in[0];
  const float* emb    = (const float*)d_in[1];
  const float* ln_g   = (const float*)d_in[2];
  const float* ln_b   = (const float*)d_in[3];
  const float* gate_w = (const float*)d_in[4];
  const float* gate_b = (const float*)d_in[5];
  const float* w1     = (const float*)d_in[6];
  const float* w2     = (const float*)d_in[7];
  const float* head_w = (const float*)d_in[8];
  const float* head_b = (const float*)d_in[9];

  float* logits  = (float*)d_out;
  float* experts = logits + (size_t)NTOK * NV;

  char* p = (char*)d_ws;
  auto carve = [&](size_t bytes) -> void* {
    void* r = (void*)p; p += (bytes + 255) & ~(size_t)255; return r;
  };
  float* h   = (float*)carve((size_t)NTOK * DM * 4);
  u16*   hbf = (u16*)  carve((size_t)NTOK * DM * 2);
  u16*   xnb = (u16*)  carve((size_t)NTOK * DM * 2);
  float* rw  = (float*)carve((size_t)NTOK * NE * 4);
  u16*   w1t = (u16*)  carve((size_t)NE * DM * DI * 2);
  u16*   w2t = (u16*)  carve((size_t)NE * DM * DI * 2);
  u16*   hwt = (u16*)  carve((size_t)NV * DM * 2);
  const size_t fixed = (size_t)(p - (char*)d_ws);
  const size_t eactOne = (size_t)NTOK * DI * 2;
  const bool batched = ws_size >= fixed + eactOne * NE;
  u16* eact = (u16*)carve(batched ? eactOne * NE : eactOne);

  const int LDSB = 131072;  // 4 x 32 KB
  (void)hipFuncSetAttribute((const void*)k_gemm256<0>,
                            hipFuncAttributeMaxDynamicSharedMemorySize, LDSB);
  (void)hipFuncSetAttribute((const void*)k_gemm256<1>,
                            hipFuncAttributeMaxDynamicSharedMemorySize, LDSB);
  (void)hipFuncSetAttribute((const void*)k_gemm256<2>,
                            hipFuncAttributeMaxDynamicSharedMemorySize, LDSB);

  const int MB = NTOK / 256;  // 32 m-blocks

  k_gather<<<dim3(NTOK), dim3(256), 0, stream>>>(x, emb, h);

  for (int l = 0; l < NL; ++l) {
    k_lngate<<<dim3(NTOK), dim3(256), 0, stream>>>(
        h, ln_g + (size_t)l * DM, ln_b + (size_t)l * DM,
        gate_w + (size_t)l * DM * NE, gate_b + (size_t)l * NE, xnb, rw);
    k_transcvt<<<dim3(DI / 32, DM / 32, NE), dim3(32, 8), 0, stream>>>(
        w1 + (size_t)l * NE * DM * DI, w1t, DM, DI);
    k_transcvt<<<dim3(DM / 32, DI / 32, NE), dim3(32, 8), 0, stream>>>(
        w2 + (size_t)l * NE * DM * DI, w2t, DI, DM);
    float* expertsL = experts + (size_t)l * NTOK * NE * DM;
    if (batched) {
      k_gemm256<1><<<dim3(NE * MB * (DI / 256)), dim3(512), LDSB, stream>>>(
          xnb, w1t, eact, nullptr, DM, MB, DI / 256,
          (size_t)0, (size_t)DM * DI, (size_t)NTOK * DI, DI);
      k_gemm256<2><<<dim3(NE * MB * (DM / 256)), dim3(512), LDSB, stream>>>(
          eact, w2t, expertsL, nullptr, DI, MB, DM / 256,
          (size_t)NTOK * DI, (size_t)DM * DI, (size_t)DM, NE * DM);
    } else {
      for (int e = 0; e < NE; ++e) {
        k_gemm256<1><<<dim3(MB * (DI / 256)), dim3(512), LDSB, stream>>>(
            xnb, w1t + (size_t)e * DM * DI, eact, nullptr, DM, MB, DI / 256,
            (size_t)0, (size_t)0, (size_t)0, DI);
        k_gemm256<2><<<dim3(MB * (DM / 256)), dim3(512), LDSB, stream>>>(
            eact, w2t + (size_t)e * DM * DI, expertsL + (size_t)e * DM, nullptr,
            DI, MB, DM / 256, (size_t)0, (size_t)0, (size_t)0, NE * DM);
      }
    }
    k_agg<<<dim3(NTOK), dim3(256), 0, stream>>>(h, hbf, expertsL, rw);
  }

  k_transcvt<<<dim3(NV / 32, DM / 32, 1), dim3(32, 8), 0, stream>>>(head_w, hwt, DM, NV);
  k_gemm256<0><<<dim3(MB * (NV / 256)), dim3(512), LDSB, stream>>>(
      hbf, hwt, logits, head_b, DM, MB, NV / 256,
      (size_t)0, (size_t)0, (size_t)0, NV);
}

// Round 18
// 2165.248 us; speedup vs baseline: 1.8394x; 1.0096x over previous
//
#include <hip/hip_runtime.h>
#include <hip/hip_bf16.h>
#include <stdint.h>

#define NTOK 8192   // B*T
#define DM   1024   // model dim
#define NE   8      // experts
#define DI   2048   // expert inner dim
#define NL   2      // layers
#define NV   32000  // vocab

#define EPW  260    // epilogue LDS row stride (floats): 1040B -> kg groups 16
                    // banks apart (2-way = free, m136) vs 256's 4-way; 16B-aligned

typedef __attribute__((ext_vector_type(8))) __bf16 bf16x8;
typedef __attribute__((ext_vector_type(4))) float  f32x4;
typedef __attribute__((ext_vector_type(4))) uint32_t u32x4;
typedef unsigned short u16;

__device__ __forceinline__ u16 f2bf(float f) {
  uint32_t u = __builtin_bit_cast(uint32_t, f);
  return (u16)((u + 0x7fffu + ((u >> 16) & 1u)) >> 16);  // RNE
}

// full-line stream stores: wave-contiguous 16B/lane -> whole 128B lines ->
// no write-allocate RFO (the R12 -11% mechanism)
__device__ __forceinline__ void nts_f32x4(float* p, f32x4 v) {
  asm volatile("global_store_dwordx4 %0, %1, off sc0 sc1 nt"
               :: "v"(p), "v"(v) : "memory");
}
__device__ __forceinline__ void nts_b128(u16* p, u32x4 v) {
  asm volatile("global_store_dwordx4 %0, %1, off sc0 sc1 nt"
               :: "v"(p), "v"(v) : "memory");
}

__device__ __forceinline__ void gload_lds16(const u16* g, void* l) {
  __builtin_amdgcn_global_load_lds(
      (const __attribute__((address_space(1))) void*)g,
      (__attribute__((address_space(3))) void*)l, 16, 0, 0);
}

// bijective chunked XCD swizzle (m204)
__device__ __forceinline__ int xcd_swz(int orig, int nwg) {
  const int x = orig & 7, i = orig >> 3;
  const int q = nwg >> 3, r = nwg & 7;
  return (x < r ? x * (q + 1) : r * (q + 1) + (x - r) * q) + i;
}

// ---------------------------------------------------------------------------
// 256x256 tile GEMM, 512 threads = 8 waves (2M x 4N), wave-tile 128x64.
// Mainloop (R12, best measured 2172us): K-half=32 units, 4 buffers (g&3),
// stage g+3 while computing g, counted vmcnt(8) steady / 4 / 0 peel. One
// barrier per K-half. Closed axes: finer cadence (R8/R13 regress), coarser
// barriers (R17: needs 6 buffers = 192KB > 160KB LDS -> impossible),
// 2 blk/CU (R6/R15 regress). [rows][32] layout + slot swizzle (conflict-0).
// EPILOGUE: LDS-staged: scatter acc to LDS [128][EPW=260] f32 per wm-half
// (R18: 260-stride spreads kg-groups 16 banks apart -> 2-way free scatter),
// barrier, linear readback, full-line nt stores + fused bias/gelu.
// EPI: 0 = +bias -> f32 (head), 1 = gelu -> bf16 (gemm1), 2 = f32 strided.
// ---------------------------------------------------------------------------
template <int EPI>
__global__ __launch_bounds__(512, 1) void k_gemm256(
    const u16* __restrict__ A0, const u16* __restrict__ W0,
    void* __restrict__ O0, const float* __restrict__ bias,
    int K, int mBlks, int nBlks,
    size_t aStride, size_t wStride, size_t oStride, int ldOut) {
  extern __shared__ char lds[];   // mainloop 4x32KB; epilogue 128*260*4 B
  const int logical = xcd_swz(blockIdx.x, gridDim.x);
  const int perE = mBlks * nBlks;
  const int e    = logical / perE;
  const int rem  = logical - e * perE;
  const int mb   = rem / nBlks;        // m outer
  const int nb   = rem - mb * nBlks;   // n inner
  const int rowBase = mb * 256;
  const int colBase = nb * 256;
  const u16* A = A0 + (size_t)e * aStride;
  const u16* W = W0 + (size_t)e * wStride;

  const int t = threadIdx.x, lane = t & 63, wave = t >> 6;
  const int wm = wave >> 2, wn = wave & 3;   // wave tile (wm*128, wn*64)
  const int fr = lane & 15, kg = lane >> 4;

  // ---- staging: chunk c (0..1023 per operand) -> row=c>>2, slotL=c&3;
  // linear LDS dest c*16; global slot = slotL ^ ((row>>2)&3) (inverse swz)
  const u16* gA[2]; const u16* gB[2]; int loA[2], loB[2];
#pragma unroll
  for (int i = 0; i < 2; ++i) {
    const int c = t + 512 * i, row = c >> 2;
    const int gs = (c & 3) ^ ((row >> 2) & 3);
    gA[i] = A + (size_t)(rowBase + row) * K + gs * 8;
    gB[i] = W + (size_t)(colBase + row) * K + gs * 8;
    loA[i] = c * 16;
    loB[i] = 16384 + c * 16;
  }

  auto stage = [&](int g) {
    char* dst = lds + (g & 3) * 32768;
#pragma unroll
    for (int i = 0; i < 2; ++i) {
      gload_lds16(gA[i] + (size_t)g * 32, dst + loA[i]);
      gload_lds16(gB[i] + (size_t)g * 32, dst + loB[i]);
    }
  };

  // ---- fragment read offsets: addr = row*64 + (kg^((fr>>2)&3))*16
  const int swzo = (kg ^ ((fr >> 2) & 3)) * 16;
  const int aOff = (wm * 128 + fr) * 64 + swzo;           // + mi*1024 (16 rows)
  const int bOff = 16384 + (wn * 64 + fr) * 64 + swzo;    // + ni*1024

  f32x4 acc[8][4] = {};
  const int NG = K >> 5;   // K-halves (>= 32 for all our shapes)

  auto khalf = [&](int g, bool doStage) {
    __builtin_amdgcn_s_barrier();
    asm volatile("" ::: "memory");
    const char* base = lds + (g & 3) * 32768;
    bf16x8 af[8], bv[4];
#pragma unroll
    for (int mi = 0; mi < 8; ++mi) af[mi] = *(const bf16x8*)(base + aOff + mi * 1024);
#pragma unroll
    for (int ni = 0; ni < 4; ++ni) bv[ni] = *(const bf16x8*)(base + bOff + ni * 1024);
    if (doStage) stage(g + 3);
    __builtin_amdgcn_s_setprio(1);
#pragma unroll
    for (int mi = 0; mi < 8; ++mi)
#pragma unroll
      for (int ni = 0; ni < 4; ++ni)
        acc[mi][ni] = __builtin_amdgcn_mfma_f32_16x16x32_bf16(
            af[mi], bv[ni], acc[mi][ni], 0, 0, 0);
    __builtin_amdgcn_s_setprio(0);
  };

  // prologue: 3 units in flight (12 loads/thread outstanding)
  stage(0); stage(1); stage(2);

#pragma unroll 1
  for (int g = 0; g < NG - 3; ++g) {
    asm volatile("s_waitcnt vmcnt(8)" ::: "memory");  // unit g resident
    khalf(g, true);
  }
  asm volatile("s_waitcnt vmcnt(8)" ::: "memory");
  khalf(NG - 3, false);
  asm volatile("s_waitcnt vmcnt(4)" ::: "memory");
  khalf(NG - 2, false);
  asm volatile("s_waitcnt vmcnt(0)" ::: "memory");
  khalf(NG - 1, false);

  // ---- LDS-staged epilogue ------------------------------------------------
  float* ep = (float*)lds;
  const int colL0 = wn * 64 + fr;
  __syncthreads();   // mainloop LDS reads drained on all waves
#pragma unroll 1
  for (int p = 0; p < 2; ++p) {
    if (wm == p) {
#pragma unroll
      for (int mi = 0; mi < 8; ++mi)
#pragma unroll
        for (int ni = 0; ni < 4; ++ni) {
          const int rl = mi * 16 + (kg << 2);
          const int cl = colL0 + ni * 16;
#pragma unroll
          for (int j = 0; j < 4; ++j)
            ep[(rl + j) * EPW + cl] = acc[mi][ni][j];
        }
    }
    __syncthreads();
    if (EPI == 1) {
      u16* O = (u16*)O0 + (size_t)e * oStride;
#pragma unroll
      for (int ii = 0; ii < 8; ++ii) {
        const int chunk = t + 512 * ii;        // 32B chunks: 128*32 = 4096
        const int rl = chunk >> 5;
        const int cl = (chunk & 31) << 3;      // 8 floats
        const f32x4 v0 = *(const f32x4*)(ep + rl * EPW + cl);
        const f32x4 v1 = *(const f32x4*)(ep + rl * EPW + cl + 4);
        float gv[8];
#pragma unroll
        for (int j = 0; j < 4; ++j) {
          gv[j]     = 0.5f * v0[j] * (1.0f + erff(v0[j] * 0.70710678118654752f));
          gv[4 + j] = 0.5f * v1[j] * (1.0f + erff(v1[j] * 0.70710678118654752f));
        }
        u32x4 pk;
        pk.x = (uint32_t)f2bf(gv[0]) | ((uint32_t)f2bf(gv[1]) << 16);
        pk.y = (uint32_t)f2bf(gv[2]) | ((uint32_t)f2bf(gv[3]) << 16);
        pk.z = (uint32_t)f2bf(gv[4]) | ((uint32_t)f2bf(gv[5]) << 16);
        pk.w = (uint32_t)f2bf(gv[6]) | ((uint32_t)f2bf(gv[7]) << 16);
        const int row = rowBase + p * 128 + rl;
        nts_b128(&O[(size_t)row * ldOut + colBase + cl], pk);
      }
    } else {
      float* O = (float*)O0 + (EPI == 2 ? (size_t)e * oStride : (size_t)0);
#pragma unroll
      for (int ii = 0; ii < 16; ++ii) {
        const int chunk = t + 512 * ii;        // 16B chunks: 128*64 = 8192
        const int rl = chunk >> 6;
        const int cl = (chunk & 63) << 2;      // 4 floats
        f32x4 v = *(const f32x4*)(ep + rl * EPW + cl);
        if (EPI == 0) v += *(const f32x4*)(bias + colBase + cl);
        const int row = rowBase + p * 128 + rl;
        nts_f32x4(&O[(size_t)row * ldOut + colBase + cl], v);
      }
    }
    __syncthreads();   // readback done before next pass overwrites LDS
  }
}

// transpose+convert: in f32 [z][R][C] -> out bf16 [z][C][R]  (R12 version)
__global__ void k_transcvt(const float* __restrict__ in, u16* __restrict__ out,
                           int R, int C) {
  const size_t bo = (size_t)blockIdx.z * R * C;
  in += bo; out += bo;
  __shared__ u16 tile[32][33];
  const int tx = threadIdx.x, ty = threadIdx.y;
  const int r0 = blockIdx.y << 5, c0 = blockIdx.x << 5;
#pragma unroll
  for (int j = 0; j < 4; ++j) {
    const int r = r0 + ty + j * 8;
    tile[ty + j * 8][tx] = f2bf(in[(size_t)r * C + c0 + tx]);
  }
  __syncthreads();
#pragma unroll
  for (int j = 0; j < 4; ++j) {
    const int c = c0 + ty + j * 8;
    out[(size_t)c * R + r0 + tx] = tile[tx][ty + j * 8];
  }
}

// embedding gather
__global__ void k_gather(const int* __restrict__ x, const float* __restrict__ emb,
                         float* __restrict__ h) {
  const int n = blockIdx.x, t = threadIdx.x;
  const int id = x[n];
  ((float4*)(h + (size_t)n * DM))[t] = ((const float4*)(emb + (size_t)id * DM))[t];
}

// fused LayerNorm (f32) -> xn bf16, + gating logits + softmax -> rw
__global__ void k_lngate(const float* __restrict__ h, const float* __restrict__ g,
                         const float* __restrict__ b, const float* __restrict__ gw,
                         const float* __restrict__ gb, u16* __restrict__ xnb,
                         float* __restrict__ rw) {
  const int n = blockIdx.x, t = threadIdx.x;
  const int wave = t >> 6, lane = t & 63;
  const float4 v = ((const float4*)(h + (size_t)n * DM))[t];
  float s = v.x + v.y + v.z + v.w;
  float q = v.x * v.x + v.y * v.y + v.z * v.z + v.w * v.w;
#pragma unroll
  for (int o = 32; o; o >>= 1) { s += __shfl_down(s, o, 64); q += __shfl_down(q, o, 64); }
  __shared__ float red[8];
  if (lane == 0) { red[wave] = s; red[wave + 4] = q; }
  __syncthreads();
  s = red[0] + red[1] + red[2] + red[3];
  q = red[4] + red[5] + red[6] + red[7];
  const float mu = s * (1.0f / DM);
  const float var = q * (1.0f / DM) - mu * mu;
  const float rs = rsqrtf(var + 1e-5f);
  const float4 gg = ((const float4*)g)[t];
  const float4 bb = ((const float4*)b)[t];
  float xv[4];
  xv[0] = (v.x - mu) * rs * gg.x + bb.x;
  xv[1] = (v.y - mu) * rs * gg.y + bb.y;
  xv[2] = (v.z - mu) * rs * gg.z + bb.z;
  xv[3] = (v.w - mu) * rs * gg.w + bb.w;
  ushort4 o4;
  o4.x = f2bf(xv[0]); o4.y = f2bf(xv[1]); o4.z = f2bf(xv[2]); o4.w = f2bf(xv[3]);
  ((ushort4*)(xnb + (size_t)n * DM))[t] = o4;
  float p[8];
#pragma unroll
  for (int e = 0; e < 8; ++e) p[e] = 0.0f;
  const float* gwp = gw + (size_t)t * 32;
#pragma unroll
  for (int j = 0; j < 4; ++j)
#pragma unroll
    for (int e = 0; e < 8; ++e) p[e] += xv[j] * gwp[j * 8 + e];
#pragma unroll
  for (int e = 0; e < 8; ++e)
#pragma unroll
    for (int o = 32; o; o >>= 1) p[e] += __shfl_down(p[e], o, 64);
  __shared__ float pr[4][8];
  if (lane == 0) {
#pragma unroll
    for (int e = 0; e < 8; ++e) pr[wave][e] = p[e];
  }
  __syncthreads();
  if (t == 0) {
    float lg[8], m = -1e30f;
#pragma unroll
    for (int e = 0; e < 8; ++e) {
      lg[e] = pr[0][e] + pr[1][e] + pr[2][e] + pr[3][e] + gb[e];
      m = fmaxf(m, lg[e]);
    }
    float ss = 0.0f;
#pragma unroll
    for (int e = 0; e < 8; ++e) { lg[e] = expf(lg[e] - m); ss += lg[e]; }
    const float inv = 1.0f / ss;
#pragma unroll
    for (int e = 0; e < 8; ++e) rw[(size_t)n * NE + e] = lg[e] * inv;
  }
}

// h += sum_e rw[n][e] * eo[n][e][:]; also emit h in bf16 for the head GEMM
__global__ void k_agg(float* __restrict__ h, u16* __restrict__ hbf,
                      const float* __restrict__ eo, const float* __restrict__ rw) {
  const int n = blockIdx.x, t = threadIdx.x;
  float w[8];
#pragma unroll
  for (int e = 0; e < 8; ++e) w[e] = rw[(size_t)n * NE + e];
  const f32x4* eo4 = (const f32x4*)(eo + (size_t)n * NE * DM);
  f32x4 a = ((f32x4*)(h + (size_t)n * DM))[t];
#pragma unroll
  for (int e = 0; e < 8; ++e) {
    const f32x4 xv = __builtin_nontemporal_load(&eo4[e * (DM / 4) + t]);
    a += w[e] * xv;
  }
  ((f32x4*)(h + (size_t)n * DM))[t] = a;
  ushort4 o4;
  o4.x = f2bf(a.x); o4.y = f2bf(a.y); o4.z = f2bf(a.z); o4.w = f2bf(a.w);
  ((ushort4*)(hbf + (size_t)n * DM))[t] = o4;
}

extern "C" void kernel_launch(void* const* d_in, const int* in_sizes, int n_in,
                              void* d_out, int out_size, void* d_ws, size_t ws_size,
                              hipStream_t stream) {
  const int*   x      = (const int*)d_in[0];
  const float* emb    = (const float*)d_in[1];
  const float* ln_g   = (const float*)d_in[2];
  const float* ln_b   = (const float*)d_in[3];
  const float* gate_w = (const float*)d_in[4];
  const float* gate_b = (const float*)d_in[5];
  const float* w1     = (const float*)d_in[6];
  const float* w2     = (const float*)d_in[7];
  const float* head_w = (const float*)d_in[8];
  const float* head_b = (const float*)d_in[9];

  float* logits  = (float*)d_out;
  float* experts = logits + (size_t)NTOK * NV;

  char* p = (char*)d_ws;
  auto carve = [&](size_t bytes) -> void* {
    void* r = (void*)p; p += (bytes + 255) & ~(size_t)255; return r;
  };
  float* h   = (float*)carve((size_t)NTOK * DM * 4);
  u16*   hbf = (u16*)  carve((size_t)NTOK * DM * 2);
  u16*   xnb = (u16*)  carve((size_t)NTOK * DM * 2);
  float* rw  = (float*)carve((size_t)NTOK * NE * 4);
  u16*   w1t = (u16*)  carve((size_t)NE * DM * DI * 2);
  u16*   w2t = (u16*)  carve((size_t)NE * DM * DI * 2);
  u16*   hwt = (u16*)  carve((size_t)NV * DM * 2);
  const size_t fixed = (size_t)(p - (char*)d_ws);
  const size_t eactOne = (size_t)NTOK * DI * 2;
  const bool batched = ws_size >= fixed + eactOne * NE;
  u16* eact = (u16*)carve(batched ? eactOne * NE : eactOne);

  const int LDSB = 128 * EPW * 4;  // 133120 B (mainloop uses first 128KB)
  (void)hipFuncSetAttribute((const void*)k_gemm256<0>,
                            hipFuncAttributeMaxDynamicSharedMemorySize, LDSB);
  (void)hipFuncSetAttribute((const void*)k_gemm256<1>,
                            hipFuncAttributeMaxDynamicSharedMemorySize, LDSB);
  (void)hipFuncSetAttribute((const void*)k_gemm256<2>,
                            hipFuncAttributeMaxDynamicSharedMemorySize, LDSB);

  const int MB = NTOK / 256;  // 32 m-blocks

  k_gather<<<dim3(NTOK), dim3(256), 0, stream>>>(x, emb, h);

  for (int l = 0; l < NL; ++l) {
    k_lngate<<<dim3(NTOK), dim3(256), 0, stream>>>(
        h, ln_g + (size_t)l * DM, ln_b + (size_t)l * DM,
        gate_w + (size_t)l * DM * NE, gate_b + (size_t)l * NE, xnb, rw);
    k_transcvt<<<dim3(DI / 32, DM / 32, NE), dim3(32, 8), 0, stream>>>(
        w1 + (size_t)l * NE * DM * DI, w1t, DM, DI);
    k_transcvt<<<dim3(DM / 32, DI / 32, NE), dim3(32, 8), 0, stream>>>(
        w2 + (size_t)l * NE * DM * DI, w2t, DI, DM);
    float* expertsL = experts + (size_t)l * NTOK * NE * DM;
    if (batched) {
      k_gemm256<1><<<dim3(NE * MB * (DI / 256)), dim3(512), LDSB, stream>>>(
          xnb, w1t, eact, nullptr, DM, MB, DI / 256,
          (size_t)0, (size_t)DM * DI, (size_t)NTOK * DI, DI);
      k_gemm256<2><<<dim3(NE * MB * (DM / 256)), dim3(512), LDSB, stream>>>(
          eact, w2t, expertsL, nullptr, DI, MB, DM / 256,
          (size_t)NTOK * DI, (size_t)DM * DI, (size_t)DM, NE * DM);
    } else {
      for (int e = 0; e < NE; ++e) {
        k_gemm256<1><<<dim3(MB * (DI / 256)), dim3(512), LDSB, stream>>>(
            xnb, w1t + (size_t)e * DM * DI, eact, nullptr, DM, MB, DI / 256,
            (size_t)0, (size_t)0, (size_t)0, DI);
        k_gemm256<2><<<dim3(MB * (DM / 256)), dim3(512), LDSB, stream>>>(
            eact, w2t + (size_t)e * DM * DI, expertsL + (size_t)e * DM, nullptr,
            DI, MB, DM / 256, (size_t)0, (size_t)0, (size_t)0, NE * DM);
      }
    }
    k_agg<<<dim3(NTOK), dim3(256), 0, stream>>>(h, hbf, expertsL, rw);
  }

  k_transcvt<<<dim3(NV / 32, DM / 32, 1), dim3(32, 8), 0, stream>>>(head_w, hwt, DM, NV);
  k_gemm256<0><<<dim3(MB * (NV / 256)), dim3(512), LDSB, stream>>>(
      hbf, hwt, logits, head_b, DM, MB, NV / 256,
      (size_t)0, (size_t)0, (size_t)0, NV);
}